// Round 6
// baseline (10397.285 us; speedup 1.0000x reference)
//
#include <hip/hip_runtime.h>
#include <cstdint>
#include <cstddef>

#define B_  1024
#define T_  100
#define H_  256

typedef _Float16 f16x8 __attribute__((ext_vector_type(8)));
typedef float    f32x16 __attribute__((ext_vector_type(16)));

__device__ __forceinline__ float sigm(float x){ return 1.0f/(1.0f + __expf(-x)); }
__device__ __forceinline__ float tanh_(float x){ return 1.0f - 2.0f/(1.0f + __expf(2.0f*x)); }

// fp16 weight pool offsets (elements) — R1 layout (gate-blocked, reference row order)
#define W_WHH1F 0
#define W_WHH1B 262144
#define W_WIH2F 524288
#define W_WIH2B 1048576
#define W_WHH2F 1572864
#define W_WHH2B 1835008
#define W_TOTAL 2097152

__global__ void conv_weights(const float* __restrict__ Whh1f, const float* __restrict__ Whh1b,
                             const float* __restrict__ Wih2f, const float* __restrict__ Wih2b,
                             const float* __restrict__ Whh2f, const float* __restrict__ Whh2b,
                             _Float16* __restrict__ dst)
{
  int idx = blockIdx.x*256 + threadIdx.x;
  if      (idx < W_WHH1B) dst[idx] = (_Float16)Whh1f[idx];
  else if (idx < W_WIH2F) dst[idx] = (_Float16)Whh1b[idx - W_WHH1B];
  else if (idx < W_WIH2B) dst[idx] = (_Float16)Wih2f[idx - W_WIH2F];
  else if (idx < W_WHH2F) dst[idx] = (_Float16)Wih2b[idx - W_WIH2B];
  else if (idx < W_WHH2B) dst[idx] = (_Float16)Whh2f[idx - W_WHH2F];
  else if (idx < W_TOTAL) dst[idx] = (_Float16)Whh2b[idx - W_WHH2B];
}

__global__ void prep_kernel(const float* __restrict__ x0, float* __restrict__ mvec){
  int b = blockIdx.x*blockDim.x + threadIdx.x;
  if (b < B_){
    float ssum = 0.0f;
    for (int t = 0; t < T_; t++) ssum += x0[b*T_ + t];
    mvec[b] = ssum * (1.0f / T_);
  }
}

__global__ void final_kernel(const float* __restrict__ pred, const float* __restrict__ mvec,
                             const float* __restrict__ bout, float* __restrict__ out){
  int idx = blockIdx.x*256 + threadIdx.x;
  if (idx < B_*T_){
    int b = idx / T_;
    out[idx] = pred[idx] + bout[0] + mvec[b];
  }
}

// ---------------- persistent kernel (plain launch; hand-rolled barriers) ----------------
struct PP {
  const float *x0, *Wih1f, *Wih1b, *b1f_ih, *b1f_hh, *b1b_ih, *b1b_hh;
  const float *b2f_ih, *b2f_hh, *b2b_ih, *b2b_hh;
  const float *Wout, *mask1, *mask2, *mask3, *mask4;
  const _Float16 *wpool;
  _Float16 *p1m, *hm1, *hm2;
  float *cbuf1, *cbuf2, *pred, *mvec;
  unsigned *ctr1, *ctr2, *ctrF;     // monotone barrier counters (zeroed per launch)
};

// Monotone-counter barrier. Counters start at 0 each launch (in-graph memset).
// Release: __threadfence + agent-scope RELEASE add. Acquire: agent-scope spin +
// __threadfence so all threads' subsequent plain loads see remote writes (G16).
__device__ __forceinline__ void bar_wait(unsigned* c, unsigned target){
  __syncthreads();
  if (threadIdx.x == 0){
    __threadfence();
    __hip_atomic_fetch_add(c, 1u, __ATOMIC_RELEASE, __HIP_MEMORY_SCOPE_AGENT);
    while (__hip_atomic_load(c, __ATOMIC_ACQUIRE, __HIP_MEMORY_SCOPE_AGENT) < target)
      __builtin_amdgcn_s_sleep(8);
  }
  __syncthreads();
  __threadfence();
}

// R1's gemm_chunk, 32-row variant (128 threads stage 32 rows x 256 cols).
// A-operand: lane holds A[m=ln31][k=lhi*8 + j]   (16B contiguous, LDS stride 264)
// B-operand: lane holds W[n=base+ln31][k=lhi*8 + j]  straight from global
// C/D:       col = ln31, row = (r&3) + 8*(r>>2) + 4*lhi
__device__ __forceinline__ void gemm32(
    f32x16 acc[4],
    const _Float16* __restrict__ Asrc, int a_stride,
    const _Float16* __restrict__ Wsrc, int w_stride,
    _Float16* Alds,                               // [32][264]
    int b0, int j0, int cw, int ln31, int lhi)
{
  const int t = threadIdx.x;        // 0..127
  #pragma unroll
  for (int i = 0; i < 8; i++){
    int u   = t + 128*i;            // 1024 uint4 = 32 rows x 32 units
    int row = u >> 5;
    int c8  = u & 31;
    uint4 v = *(const uint4*)(Asrc + (size_t)(b0 + row)*a_stride + c8*8);
    *(uint4*)(Alds + row*264 + c8*8) = v;
  }
  __syncthreads();
  const _Float16* arow = Alds + ln31*264 + lhi*8;
  const int nbase = j0 + cw*32 + ln31;
  const int kq    = lhi*8;
  #pragma unroll
  for (int kk = 0; kk < 16; kk++){
    f16x8 a = *(const f16x8*)(arow + kk*16);
    #pragma unroll
    for (int g = 0; g < 4; g++){
      const _Float16* wp = Wsrc + (size_t)(g*256 + nbase)*w_stride + kk*16 + kq;
      f16x8 bw = *(const f16x8*)wp;
      acc[g] = __builtin_amdgcn_mfma_f32_32x32x16_f16(a, bw, acc[g], 0, 0, 0);
    }
  }
  __syncthreads();
}

__global__ __launch_bounds__(128) void lstm_persist(PP p){
  __shared__ __align__(16) _Float16 Alds[32*264];   // 16.5 KB
  const int btile = blockIdx.x;          // 32 tiles of 32 rows
  const int j0    = blockIdx.y*64;       // 4 tiles of 64 cols
  const int dir   = blockIdx.z;
  const int b0    = btile*32;
  const int grp   = dir*32 + btile;      // recurrence group: 4 blocks (j0 tiles)
  const int lane  = threadIdx.x & 63;
  const int cw    = threadIdx.x >> 6;    // 2 waves: j-halves
  const int ln31  = lane & 31, lhi = lane >> 5;
  const int jj    = j0 + cw*32 + ln31;   // this lane's j (holds ALL 4 gates)

  // ---------------- Phase 1: layer 1 ----------------
  {
    const _Float16* Whh = p.wpool + (dir ? W_WHH1B : W_WHH1F);
    const float* Wih = dir ? p.Wih1b : p.Wih1f;
    const float* bih = dir ? p.b1b_ih : p.b1f_ih;
    const float* bhh = dir ? p.b1b_hh : p.b1f_hh;
    float wi0[4], wi1[4], bs[4];
    #pragma unroll
    for (int g = 0; g < 4; g++){
      int n = g*256 + jj;
      wi0[g] = Wih[n*2 + 0];
      wi1[g] = Wih[n*2 + 1];
      bs[g]  = bih[n] + bhh[n];
    }
    float* cp = p.cbuf1 + (size_t)dir*B_*H_;

    for (int s = 0; s < T_; s++){
      const _Float16* hmcur = p.hm1 + (size_t)((s & 1)*2 + dir)*B_*H_;
      _Float16* hmnxt = p.hm1 + (size_t)(((s+1) & 1)*2 + dir)*B_*H_;
      const int tin = dir ? (T_-1-s) : s;

      f32x16 acc[4];
      #pragma unroll
      for (int g = 0; g < 4; g++)
        #pragma unroll
        for (int e = 0; e < 16; e++) acc[g][e] = 0.0f;

      gemm32(acc, hmcur, H_, Whh, H_, Alds, b0, j0, cw, ln31, lhi);

      #pragma unroll
      for (int r = 0; r < 16; r++){
        int row = (r & 3) + 8*(r >> 2) + 4*lhi;
        int b   = b0 + row;
        float mv = p.mvec[b];
        float xd = p.x0[b*T_ + tin] - mv;
        float gi = acc[0][r] + xd*wi0[0] + mv*wi1[0] + bs[0];
        float gf = acc[1][r] + xd*wi0[1] + mv*wi1[1] + bs[1];
        float gg = acc[2][r] + xd*wi0[2] + mv*wi1[2] + bs[2];
        float go = acc[3][r] + xd*wi0[3] + mv*wi1[3] + bs[3];
        float ii = sigm(gi), ff = sigm(gf), g2 = tanh_(gg), oo = sigm(go);
        size_t ci = (size_t)b*H_ + jj;
        float cn = ff*cp[ci] + ii*g2;
        cp[ci] = cn;
        float h = oo*tanh_(cn);
        hmnxt[ci] = (_Float16)(h * p.mask1[ci]);
        p.p1m[((size_t)s*B_ + b)*512 + dir*256 + jj] =
            (_Float16)(h * p.mask2[(size_t)b*512 + dir*256 + jj]);
      }
      if (s < T_-1) bar_wait(&p.ctr1[grp*16], (unsigned)(s+1)*4);
    }
  }

  // ---------------- phase boundary: full device barrier ----------------
  bar_wait(p.ctrF, 256u);

  // ---------------- Phase 2: layer 2 ----------------
  {
    const _Float16* Wih = p.wpool + (dir ? W_WIH2B : W_WIH2F);
    const _Float16* Whh = p.wpool + (dir ? W_WHH2B : W_WHH2F);
    const float* bih = dir ? p.b2b_ih : p.b2f_ih;
    const float* bhh = dir ? p.b2b_hh : p.b2f_hh;
    float bs[4];
    #pragma unroll
    for (int g = 0; g < 4; g++)
      bs[g] = bih[g*256 + jj] + bhh[g*256 + jj];
    float wo = p.Wout[dir*256 + jj];
    float* cp = p.cbuf2 + (size_t)dir*B_*H_;

    for (int s = 0; s < T_; s++){
      const int tin = dir ? (T_-1-s) : s;
      const _Float16* Ain = p.p1m + (size_t)tin*B_*512;
      const _Float16* hmcur = p.hm2 + (size_t)((s & 1)*2 + dir)*B_*H_;
      _Float16* hmnxt = p.hm2 + (size_t)(((s+1) & 1)*2 + dir)*B_*H_;

      f32x16 acc[4];
      #pragma unroll
      for (int g = 0; g < 4; g++)
        #pragma unroll
        for (int e = 0; e < 16; e++) acc[g][e] = 0.0f;

      gemm32(acc, Ain,       512, Wih,       512, Alds, b0, j0, cw, ln31, lhi);
      gemm32(acc, Ain + 256, 512, Wih + 256, 512, Alds, b0, j0, cw, ln31, lhi);
      gemm32(acc, hmcur,     H_,  Whh,       H_,  Alds, b0, j0, cw, ln31, lhi);

      #pragma unroll
      for (int r = 0; r < 16; r++){
        int row = (r & 3) + 8*(r >> 2) + 4*lhi;
        int b   = b0 + row;
        float gi = acc[0][r] + bs[0];
        float gf = acc[1][r] + bs[1];
        float gg = acc[2][r] + bs[2];
        float go = acc[3][r] + bs[3];
        float ii = sigm(gi), ff = sigm(gf), g2 = tanh_(gg), oo = sigm(go);
        size_t ci = (size_t)b*H_ + jj;
        float cn = ff*cp[ci] + ii*g2;
        cp[ci] = cn;
        float h = oo*tanh_(cn);
        hmnxt[ci] = (_Float16)(h * p.mask3[ci]);
        float contrib = h * p.mask4[(size_t)b*512 + dir*256 + jj] * wo;
        contrib += __shfl_xor(contrib, 16);
        contrib += __shfl_xor(contrib, 8);
        contrib += __shfl_xor(contrib, 4);
        contrib += __shfl_xor(contrib, 2);
        contrib += __shfl_xor(contrib, 1);
        if (ln31 == 0) atomicAdd(&p.pred[(size_t)b*T_ + s], contrib);
      }
      if (s < T_-1) bar_wait(&p.ctr2[grp*16], (unsigned)(s+1)*4);
    }
  }
}

extern "C" void kernel_launch(void* const* d_in, const int* in_sizes, int n_in,
                              void* d_out, int out_size, void* d_ws, size_t ws_size,
                              hipStream_t stream)
{
  (void)in_sizes; (void)n_in; (void)out_size; (void)ws_size;
  const float* x0    = (const float*)d_in[0];
  const float* Wih1f = (const float*)d_in[1];
  const float* Whh1f = (const float*)d_in[2];
  const float* bih1f = (const float*)d_in[3];
  const float* bhh1f = (const float*)d_in[4];
  const float* Wih1b = (const float*)d_in[5];
  const float* Whh1b = (const float*)d_in[6];
  const float* bih1b = (const float*)d_in[7];
  const float* bhh1b = (const float*)d_in[8];
  const float* Wih2f = (const float*)d_in[9];
  const float* Whh2f = (const float*)d_in[10];
  const float* bih2f = (const float*)d_in[11];
  const float* bhh2f = (const float*)d_in[12];
  const float* Wih2b = (const float*)d_in[13];
  const float* Whh2b = (const float*)d_in[14];
  const float* bih2b = (const float*)d_in[15];
  const float* bhh2b = (const float*)d_in[16];
  const float* Wout  = (const float*)d_in[17];
  const float* bout  = (const float*)d_in[18];
  const float* mask1 = (const float*)d_in[19];
  const float* mask2 = (const float*)d_in[20];
  const float* mask3 = (const float*)d_in[21];
  const float* mask4 = (const float*)d_in[22];
  float* out = (float*)d_out;

  char* ws = (char*)d_ws;
  size_t off = 0;
  _Float16* wpool = (_Float16*)(ws + off); off += (size_t)W_TOTAL*2;      // 4.2 MB
  _Float16* p1m   = (_Float16*)(ws + off); off += (size_t)T_*B_*512*2;    // 104.8 MB
  // ---- zeroed region (contiguous; reset inside the graph every launch) ----
  char* zbase = ws + off;
  float* pred  = (float*)(ws + off); off += (size_t)B_*T_*4;
  float* mvec  = (float*)(ws + off); off += (size_t)B_*4;
  float* cbuf1 = (float*)(ws + off); off += (size_t)2*B_*H_*4;
  float* cbuf2 = (float*)(ws + off); off += (size_t)2*B_*H_*4;
  _Float16* hm1 = (_Float16*)(ws + off); off += (size_t)2*2*B_*H_*2;
  _Float16* hm2 = (_Float16*)(ws + off); off += (size_t)2*2*B_*H_*2;
  unsigned* ctr1 = (unsigned*)(ws + off); off += 64*16*4;   // 64 groups, 64B stride
  unsigned* ctr2 = (unsigned*)(ws + off); off += 64*16*4;
  unsigned* ctrF = (unsigned*)(ws + off); off += 64;
  size_t zbytes = (size_t)((ws + off) - zbase);

  hipMemsetAsync(zbase, 0, zbytes, stream);
  conv_weights<<<dim3(W_TOTAL/256), dim3(256), 0, stream>>>(
      Whh1f, Whh1b, Wih2f, Wih2b, Whh2f, Whh2b, wpool);
  prep_kernel<<<dim3(4), dim3(256), 0, stream>>>(x0, mvec);

  PP prm;
  prm.x0 = x0; prm.Wih1f = Wih1f; prm.Wih1b = Wih1b;
  prm.b1f_ih = bih1f; prm.b1f_hh = bhh1f; prm.b1b_ih = bih1b; prm.b1b_hh = bhh1b;
  prm.b2f_ih = bih2f; prm.b2f_hh = bhh2f; prm.b2b_ih = bih2b; prm.b2b_hh = bhh2b;
  prm.Wout = Wout; prm.mask1 = mask1; prm.mask2 = mask2; prm.mask3 = mask3; prm.mask4 = mask4;
  prm.wpool = wpool;
  prm.p1m = p1m; prm.hm1 = hm1; prm.hm2 = hm2;
  prm.cbuf1 = cbuf1; prm.cbuf2 = cbuf2; prm.pred = pred; prm.mvec = mvec;
  prm.ctr1 = ctr1; prm.ctr2 = ctr2; prm.ctrF = ctrF;

  lstm_persist<<<dim3(32, 4, 2), dim3(128), 0, stream>>>(prm);

  final_kernel<<<dim3((B_*T_ + 255)/256), dim3(256), 0, stream>>>(pred, mvec, bout, out);
}

// Round 7
// 7469.227 us; speedup vs baseline: 1.3920x; 1.3920x over previous
//
#include <hip/hip_runtime.h>
#include <cstdint>
#include <cstddef>

#define B_  1024
#define T_  100
#define H_  256

typedef _Float16 f16x8 __attribute__((ext_vector_type(8)));
typedef float    f32x16 __attribute__((ext_vector_type(16)));

#define LSTR 776            // LDS A-row stride in fp16 elements (768 + 8)
#define LSTRD (LSTR/2)      // dword stride = 388

__device__ __forceinline__ float sigm(float x){ return 1.0f/(1.0f + __expf(-x)); }
__device__ __forceinline__ float tanh_(float x){ return 1.0f - 2.0f/(1.0f + __expf(2.0f*x)); }

// fp16 weight pool offsets (elements) — gate-blocked, reference row order
#define W_WHH1F 0
#define W_WHH1B 262144
#define W_WIH2F 524288
#define W_WIH2B 1048576
#define W_WHH2F 1572864
#define W_WHH2B 1835008
#define W_TOTAL 2097152

__global__ void conv_weights(const float* __restrict__ Whh1f, const float* __restrict__ Whh1b,
                             const float* __restrict__ Wih2f, const float* __restrict__ Wih2b,
                             const float* __restrict__ Whh2f, const float* __restrict__ Whh2b,
                             _Float16* __restrict__ dst)
{
  int idx = blockIdx.x*256 + threadIdx.x;
  if      (idx < W_WHH1B) dst[idx] = (_Float16)Whh1f[idx];
  else if (idx < W_WIH2F) dst[idx] = (_Float16)Whh1b[idx - W_WHH1B];
  else if (idx < W_WIH2B) dst[idx] = (_Float16)Wih2f[idx - W_WIH2F];
  else if (idx < W_WHH2F) dst[idx] = (_Float16)Wih2b[idx - W_WIH2B];
  else if (idx < W_WHH2B) dst[idx] = (_Float16)Whh2f[idx - W_WHH2F];
  else if (idx < W_TOTAL) dst[idx] = (_Float16)Whh2b[idx - W_WHH2B];
}

__global__ void prep_kernel(const float* __restrict__ x0, float* __restrict__ mvec){
  int b = blockIdx.x*blockDim.x + threadIdx.x;
  if (b < B_){
    float ssum = 0.0f;
    for (int t = 0; t < T_; t++) ssum += x0[b*T_ + t];
    mvec[b] = ssum * (1.0f / T_);
  }
}

__global__ void final_kernel(const float* __restrict__ pred, const float* __restrict__ mvec,
                             const float* __restrict__ bout, float* __restrict__ out){
  int idx = blockIdx.x*256 + threadIdx.x;
  if (idx < B_*T_){
    int b = idx / T_;
    out[idx] = pred[idx] + bout[0] + mvec[b];
  }
}

struct PP {
  const float *x0, *Wih1f, *Wih1b, *b1f_ih, *b1f_hh, *b1b_ih, *b1b_hh;
  const float *b2f_ih, *b2f_hh, *b2b_ih, *b2b_hh;
  const float *Wout, *mask1, *mask2, *mask3, *mask4;
  const _Float16 *wpool;
  _Float16 *p1m;
  unsigned short *hm1, *hm2;       // comm buffers, accessed with scoped atomics
  float *cbuf1, *cbuf2, *pred, *mvec;
  unsigned *ctr1, *ctr2, *ctrF;
};

// Fence-free group barrier: comm data travels via sc-flagged (agent-scope
// relaxed) atomics that hit the device coherence point directly — no L2
// writeback/invalidate needed. Writer drains vmcnt, then relaxed add.
__device__ __forceinline__ void bar_group(unsigned* c, unsigned target){
  __syncthreads();
  if (threadIdx.x == 0){
    asm volatile("s_waitcnt vmcnt(0)" ::: "memory");
    __hip_atomic_fetch_add(c, 1u, __ATOMIC_RELAXED, __HIP_MEMORY_SCOPE_AGENT);
    while (__hip_atomic_load(c, __ATOMIC_RELAXED, __HIP_MEMORY_SCOPE_AGENT) < target)
      __builtin_amdgcn_s_sleep(2);
  }
  __syncthreads();
}

// K-loop over one 128-wide K chunk: 8 kk x 4 gates MFMA.
// A from LDS (stride LSTR); W from global (L2-resident, never invalidated).
__device__ __forceinline__ void kchunk(f32x16 acc[4], const _Float16* Alds,
                                       const _Float16* Wsrc, int wstride, int koff,
                                       int kbase, int nb, int ln31, int lhi){
  const _Float16* arow = Alds + ln31*LSTR + kbase + lhi*8;
  #pragma unroll
  for (int kk = 0; kk < 8; kk++){
    f16x8 a = *(const f16x8*)(arow + kk*16);
    #pragma unroll
    for (int g = 0; g < 4; g++){
      const _Float16* wp = Wsrc + (size_t)(g*256 + nb)*wstride + koff + kk*16 + lhi*8;
      f16x8 bw = *(const f16x8*)wp;
      acc[g] = __builtin_amdgcn_mfma_f32_32x32x16_f16(a, bw, acc[g], 0, 0, 0);
    }
  }
}

// Stage 32 rows x 256 cols of comm data (hm) via agent-scope dword atomic loads.
__device__ __forceinline__ void stage_hm(_Float16* Alds, const unsigned short* src,
                                         int ldsDwOff){
  const unsigned* s32 = (const unsigned*)src;
  unsigned* d32 = (unsigned*)Alds;
  int t = threadIdx.x;
  #pragma unroll
  for (int i = 0; i < 32; i++){
    int u = t + 128*i;               // 4096 dwords = 32 rows x 128 dwords
    int row = u >> 7, dcol = u & 127;
    unsigned v = __hip_atomic_load(s32 + (size_t)row*128 + dcol,
                                   __ATOMIC_RELAXED, __HIP_MEMORY_SCOPE_AGENT);
    d32[row*LSTRD + ldsDwOff + dcol] = v;
  }
}

// Stage 32 rows x 512 cols of p1m (plain, stable after phase barrier).
__device__ __forceinline__ void stage_p1m(_Float16* Alds, const _Float16* src){
  int t = threadIdx.x;
  #pragma unroll
  for (int i = 0; i < 16; i++){
    int u = t + 128*i;               // 2048 uint4 = 32 rows x 64 uint4
    int row = u >> 6, qcol = u & 63;
    uint4 v = *(const uint4*)(src + (size_t)row*512 + qcol*8);
    *(uint4*)(Alds + row*LSTR + qcol*8) = v;
  }
}

__global__ __launch_bounds__(128) void lstm_persist(PP p){
  __shared__ __align__(16) _Float16 Alds[32*LSTR];   // 48.5 KB (also reduce buf)
  const int btile = blockIdx.x;          // 32 tiles of 32 rows
  const int jtile = blockIdx.y;          // 8 tiles of 32 j-cols
  const int dir   = blockIdx.z;
  const int b0    = btile*32;
  const int grp   = dir*32 + btile;      // recurrence group: 8 jtile blocks
  const int lane  = threadIdx.x & 63;
  const int wv    = threadIdx.x >> 6;    // K-split wave id
  const int ln31  = lane & 31, lhi = lane >> 5;
  const int nb    = jtile*32 + ln31;     // this lane's j (all 4 gates in acc[4])
  const int jj    = nb;
  float* red = (float*)Alds;             // 16 KB reduction view (post-K reuse)

  // ---------------- Phase 1: layer 1 ----------------
  {
    const _Float16* Whh = p.wpool + (dir ? W_WHH1B : W_WHH1F);
    const float* Wih = dir ? p.Wih1b : p.Wih1f;
    const float* bih = dir ? p.b1b_ih : p.b1f_ih;
    const float* bhh = dir ? p.b1b_hh : p.b1f_hh;
    float wi0[4], wi1[4], bs[4];
    #pragma unroll
    for (int g = 0; g < 4; g++){
      int n = g*256 + jj;
      wi0[g] = Wih[n*2 + 0];
      wi1[g] = Wih[n*2 + 1];
      bs[g]  = bih[n] + bhh[n];
    }
    float* cp = p.cbuf1 + (size_t)dir*B_*H_;

    for (int s = 0; s < T_; s++){
      const unsigned short* hmcur = p.hm1 + (size_t)((s & 1)*2 + dir)*B_*H_ + (size_t)b0*H_;
      unsigned short* hmnxt = p.hm1 + (size_t)(((s+1) & 1)*2 + dir)*B_*H_;
      const int tin = dir ? (T_-1-s) : s;

      stage_hm(Alds, hmcur, 0);
      __syncthreads();

      f32x16 acc[4];
      #pragma unroll
      for (int g = 0; g < 4; g++)
        #pragma unroll
        for (int e = 0; e < 16; e++) acc[g][e] = 0.0f;

      // K=256 split: wave wv covers kbase = wv*128
      kchunk(acc, Alds, Whh, H_, wv*128, wv*128, nb, ln31, lhi);

      __syncthreads();
      if (wv == 1){
        #pragma unroll
        for (int g = 0; g < 4; g++)
          #pragma unroll
          for (int e = 0; e < 16; e++) red[(g*16+e)*64 + lane] = acc[g][e];
      }
      __syncthreads();
      if (wv == 0){
        #pragma unroll
        for (int g = 0; g < 4; g++)
          #pragma unroll
          for (int e = 0; e < 16; e++) acc[g][e] += red[(g*16+e)*64 + lane];

        #pragma unroll
        for (int r = 0; r < 16; r++){
          int row = (r & 3) + 8*(r >> 2) + 4*lhi;
          int b   = b0 + row;
          float mv = p.mvec[b];
          float xd = p.x0[b*T_ + tin] - mv;
          float gi = acc[0][r] + xd*wi0[0] + mv*wi1[0] + bs[0];
          float gf = acc[1][r] + xd*wi0[1] + mv*wi1[1] + bs[1];
          float gg = acc[2][r] + xd*wi0[2] + mv*wi1[2] + bs[2];
          float go = acc[3][r] + xd*wi0[3] + mv*wi1[3] + bs[3];
          float ii = sigm(gi), ff = sigm(gf), g2 = tanh_(gg), oo = sigm(go);
          size_t ci = (size_t)b*H_ + jj;
          float cn = ff*cp[ci] + ii*g2;
          cp[ci] = cn;
          float h = oo*tanh_(cn);
          unsigned short hb = __builtin_bit_cast(unsigned short,
                                (_Float16)(h * p.mask1[ci]));
          __hip_atomic_store(&hmnxt[ci], hb, __ATOMIC_RELAXED, __HIP_MEMORY_SCOPE_AGENT);
          p.p1m[((size_t)s*B_ + b)*512 + dir*256 + jj] =
              (_Float16)(h * p.mask2[(size_t)b*512 + dir*256 + jj]);
        }
      }
      if (s < T_-1) bar_group(&p.ctr1[grp*16], (unsigned)(s+1)*8);
    }
  }

  // ---------------- phase boundary: one full fenced barrier ----------------
  __syncthreads();
  __threadfence();                                // release: write back p1m etc.
  if (threadIdx.x == 0){
    __hip_atomic_fetch_add(p.ctrF, 1u, __ATOMIC_RELAXED, __HIP_MEMORY_SCOPE_AGENT);
    while (__hip_atomic_load(p.ctrF, __ATOMIC_RELAXED, __HIP_MEMORY_SCOPE_AGENT) < 512u)
      __builtin_amdgcn_s_sleep(8);
  }
  __syncthreads();
  __threadfence();                                // acquire: invalidate for p1m reads

  // ---------------- Phase 2: layer 2 ----------------
  {
    const _Float16* Wih = p.wpool + (dir ? W_WIH2B : W_WIH2F);
    const _Float16* Whh = p.wpool + (dir ? W_WHH2B : W_WHH2F);
    const float* bih = dir ? p.b2b_ih : p.b2f_ih;
    const float* bhh = dir ? p.b2b_hh : p.b2f_hh;
    float bs[4];
    #pragma unroll
    for (int g = 0; g < 4; g++)
      bs[g] = bih[g*256 + jj] + bhh[g*256 + jj];
    float wo = p.Wout[dir*256 + jj];
    float* cp = p.cbuf2 + (size_t)dir*B_*H_;

    for (int s = 0; s < T_; s++){
      const int tin = dir ? (T_-1-s) : s;
      const _Float16* Ap = p.p1m + (size_t)tin*B_*512 + (size_t)b0*512;
      const unsigned short* hmcur = p.hm2 + (size_t)((s & 1)*2 + dir)*B_*H_ + (size_t)b0*H_;
      unsigned short* hmnxt = p.hm2 + (size_t)(((s+1) & 1)*2 + dir)*B_*H_;

      stage_p1m(Alds, Ap);           // cols 0..511 (plain)
      stage_hm(Alds, hmcur, 256);    // cols 512..767 (atomic dwords)
      __syncthreads();

      f32x16 acc[4];
      #pragma unroll
      for (int g = 0; g < 4; g++)
        #pragma unroll
        for (int e = 0; e < 16; e++) acc[g][e] = 0.0f;

      // K=768 split: wave wv covers chunks 3wv..3wv+2
      #pragma unroll
      for (int ci = 0; ci < 3; ci++){
        int c = wv*3 + ci;
        if (c < 4) kchunk(acc, Alds, Wih, 512, c*128,     c*128, nb, ln31, lhi);
        else       kchunk(acc, Alds, Whh, H_,  (c-4)*128, c*128, nb, ln31, lhi);
      }

      __syncthreads();
      if (wv == 1){
        #pragma unroll
        for (int g = 0; g < 4; g++)
          #pragma unroll
          for (int e = 0; e < 16; e++) red[(g*16+e)*64 + lane] = acc[g][e];
      }
      __syncthreads();
      if (wv == 0){
        #pragma unroll
        for (int g = 0; g < 4; g++)
          #pragma unroll
          for (int e = 0; e < 16; e++) acc[g][e] += red[(g*16+e)*64 + lane];

        #pragma unroll
        for (int r = 0; r < 16; r++){
          int row = (r & 3) + 8*(r >> 2) + 4*lhi;
          int b   = b0 + row;
          float gi = acc[0][r] + bs[0];
          float gf = acc[1][r] + bs[1];
          float gg = acc[2][r] + bs[2];
          float go = acc[3][r] + bs[3];
          float ii = sigm(gi), ff = sigm(gf), g2 = tanh_(gg), oo = sigm(go);
          size_t ci2 = (size_t)b*H_ + jj;
          float cn = ff*cp[ci2] + ii*g2;
          cp[ci2] = cn;
          float h = oo*tanh_(cn);
          unsigned short hb = __builtin_bit_cast(unsigned short,
                                (_Float16)(h * p.mask3[ci2]));
          __hip_atomic_store(&hmnxt[ci2], hb, __ATOMIC_RELAXED, __HIP_MEMORY_SCOPE_AGENT);
          float contrib = h * p.mask4[(size_t)b*512 + dir*256 + jj] * wo;
          contrib += __shfl_xor(contrib, 16);
          contrib += __shfl_xor(contrib, 8);
          contrib += __shfl_xor(contrib, 4);
          contrib += __shfl_xor(contrib, 2);
          contrib += __shfl_xor(contrib, 1);
          if (ln31 == 0) atomicAdd(&p.pred[(size_t)b*T_ + s], contrib);
        }
      }
      if (s < T_-1) bar_group(&p.ctr2[grp*16], (unsigned)(s+1)*8);
    }
  }
}

extern "C" void kernel_launch(void* const* d_in, const int* in_sizes, int n_in,
                              void* d_out, int out_size, void* d_ws, size_t ws_size,
                              hipStream_t stream)
{
  (void)in_sizes; (void)n_in; (void)out_size; (void)ws_size;
  const float* x0    = (const float*)d_in[0];
  const float* Wih1f = (const float*)d_in[1];
  const float* Whh1f = (const float*)d_in[2];
  const float* bih1f = (const float*)d_in[3];
  const float* bhh1f = (const float*)d_in[4];
  const float* Wih1b = (const float*)d_in[5];
  const float* Whh1b = (const float*)d_in[6];
  const float* bih1b = (const float*)d_in[7];
  const float* bhh1b = (const float*)d_in[8];
  const float* Wih2f = (const float*)d_in[9];
  const float* Whh2f = (const float*)d_in[10];
  const float* bih2f = (const float*)d_in[11];
  const float* bhh2f = (const float*)d_in[12];
  const float* Wih2b = (const float*)d_in[13];
  const float* Whh2b = (const float*)d_in[14];
  const float* bih2b = (const float*)d_in[15];
  const float* bhh2b = (const float*)d_in[16];
  const float* Wout  = (const float*)d_in[17];
  const float* bout  = (const float*)d_in[18];
  const float* mask1 = (const float*)d_in[19];
  const float* mask2 = (const float*)d_in[20];
  const float* mask3 = (const float*)d_in[21];
  const float* mask4 = (const float*)d_in[22];
  float* out = (float*)d_out;

  char* ws = (char*)d_ws;
  size_t off = 0;
  _Float16* wpool = (_Float16*)(ws + off); off += (size_t)W_TOTAL*2;      // 4.2 MB
  _Float16* p1m   = (_Float16*)(ws + off); off += (size_t)T_*B_*512*2;    // 104.8 MB
  // ---- zeroed region (contiguous; reset inside the graph every launch) ----
  char* zbase = ws + off;
  float* pred  = (float*)(ws + off); off += (size_t)B_*T_*4;
  float* mvec  = (float*)(ws + off); off += (size_t)B_*4;
  float* cbuf1 = (float*)(ws + off); off += (size_t)2*B_*H_*4;
  float* cbuf2 = (float*)(ws + off); off += (size_t)2*B_*H_*4;
  unsigned short* hm1 = (unsigned short*)(ws + off); off += (size_t)2*2*B_*H_*2;
  unsigned short* hm2 = (unsigned short*)(ws + off); off += (size_t)2*2*B_*H_*2;
  unsigned* ctr1 = (unsigned*)(ws + off); off += 64*16*4;
  unsigned* ctr2 = (unsigned*)(ws + off); off += 64*16*4;
  unsigned* ctrF = (unsigned*)(ws + off); off += 64;
  size_t zbytes = (size_t)((ws + off) - zbase);

  hipMemsetAsync(zbase, 0, zbytes, stream);
  conv_weights<<<dim3(W_TOTAL/256), dim3(256), 0, stream>>>(
      Whh1f, Whh1b, Wih2f, Wih2b, Whh2f, Whh2b, wpool);
  prep_kernel<<<dim3(4), dim3(256), 0, stream>>>(x0, mvec);

  PP prm;
  prm.x0 = x0; prm.Wih1f = Wih1f; prm.Wih1b = Wih1b;
  prm.b1f_ih = bih1f; prm.b1f_hh = bhh1f; prm.b1b_ih = bih1b; prm.b1b_hh = bhh1b;
  prm.b2f_ih = bih2f; prm.b2f_hh = bhh2f; prm.b2b_ih = bih2b; prm.b2b_hh = bhh2b;
  prm.Wout = Wout; prm.mask1 = mask1; prm.mask2 = mask2; prm.mask3 = mask3; prm.mask4 = mask4;
  prm.wpool = wpool;
  prm.p1m = p1m; prm.hm1 = hm1; prm.hm2 = hm2;
  prm.cbuf1 = cbuf1; prm.cbuf2 = cbuf2; prm.pred = pred; prm.mvec = mvec;
  prm.ctr1 = ctr1; prm.ctr2 = ctr2; prm.ctrF = ctrF;

  lstm_persist<<<dim3(32, 8, 2), dim3(128), 0, stream>>>(prm);

  final_kernel<<<dim3((B_*T_ + 255)/256), dim3(256), 0, stream>>>(pred, mvec, bout, out);
}